// Round 4
// baseline (125.189 us; speedup 1.0000x reference)
//
#include <hip/hip_runtime.h>
#include <hip/hip_bf16.h>
#include <stdint.h>

#define TOKENS 16384   // N=4 * L=4096
#define LSEQ 4096
#define WPAD 72        // padded row length (shorts) for M/vw/U tiles

typedef short bf16x8 __attribute__((ext_vector_type(8)));
typedef float f32x4 __attribute__((ext_vector_type(4)));

typedef __attribute__((address_space(1))) void as1_t;
typedef __attribute__((address_space(3))) void as3_t;

__device__ __forceinline__ unsigned short f2bf(float x) {
  __hip_bfloat16 t = __float2bfloat16(x);
  return *reinterpret_cast<unsigned short*>(&t);
}

__device__ __forceinline__ bf16x8 pack8(float4 a, float4 b) {
  bf16x8 t;
  t[0] = (short)f2bf(a.x); t[1] = (short)f2bf(a.y);
  t[2] = (short)f2bf(a.z); t[3] = (short)f2bf(a.w);
  t[4] = (short)f2bf(b.x); t[5] = (short)f2bf(b.y);
  t[6] = (short)f2bf(b.z); t[7] = (short)f2bf(b.w);
  return t;
}

__device__ __forceinline__ void async16(const void* g, void* lds) {
  __builtin_amdgcn_global_load_lds((as1_t*)const_cast<void*>(g),
                                   (as3_t*)lds, 16, 0, 0);
}

// ---------------- fc_w f32 -> bf16 ----------------
__global__ __launch_bounds__(256) void cvt_bf16(const float* __restrict__ s,
                                                unsigned short* __restrict__ d,
                                                int n4) {
  int i = blockIdx.x * 256 + threadIdx.x;
  if (i < n4) {
    float4 f = ((const float4*)s)[i];
    union { unsigned short us[4]; uint2 u2; } pk;
    pk.us[0] = f2bf(f.x); pk.us[1] = f2bf(f.y);
    pk.us[2] = f2bf(f.z); pk.us[3] = f2bf(f.w);
    ((uint2*)d)[i] = pk.u2;
  }
}

// ---------------- prep: M[f][e] = sum_d qw[d][f]*kw[d][e]; vw -> bf16 ----------------
__global__ __launch_bounds__(1024) void prep_weights(
    const float* __restrict__ qw, const float* __restrict__ kw,
    const float* __restrict__ vw, unsigned short* __restrict__ Mout,
    unsigned short* __restrict__ vwout) {
  __shared__ float ql[4096], kl[4096];
  const int t = threadIdx.x;
  ((float4*)ql)[t] = ((const float4*)qw)[t];
  ((float4*)kl)[t] = ((const float4*)kw)[t];
  {
    float4 f = ((const float4*)vw)[t];
    union { unsigned short us[4]; uint2 u2; } pk;
    pk.us[0] = f2bf(f.x); pk.us[1] = f2bf(f.y);
    pk.us[2] = f2bf(f.z); pk.us[3] = f2bf(f.w);
    ((uint2*)vwout)[t] = pk.u2;
  }
  __syncthreads();
  const int f = t >> 4;            // 0..63  (q raw dim)
  const int e0 = (t & 15) * 4;     // 0..60  (k raw dim block)
  float acc0 = 0.f, acc1 = 0.f, acc2 = 0.f, acc3 = 0.f;
#pragma unroll 8
  for (int d = 0; d < 64; ++d) {
    const float qv = ql[d * 64 + f];
    const float4 kv = *(const float4*)&kl[d * 64 + e0];
    acc0 += qv * kv.x; acc1 += qv * kv.y; acc2 += qv * kv.z; acc3 += qv * kv.w;
  }
  union { unsigned short us[4]; uint2 u2; } pk;
  pk.us[0] = f2bf(acc0); pk.us[1] = f2bf(acc1);
  pk.us[2] = f2bf(acc2); pk.us[3] = f2bf(acc3);
  *(uint2*)&Mout[f * 64 + e0] = pk.u2;
}

// ---------------- fused attention: one token per wave, 8 waves/block ----------------
// S^T = (Rk @ M^T) @ Rq^T ; v4 = Rv @ vw^T ; O = P @ v4.
// mfma convention (HW-validated R2/R3): mfma(fragA(X), fragA(Y)) = X @ Y^T,
// fragA: lane holds X[row=l&15][k=(l>>4)*8+j]; C: col=l&15, row=(l>>4)*4+r.
__global__ __launch_bounds__(512, 8) void attn4(
    const float* __restrict__ q, const float* __restrict__ k,
    const float* __restrict__ v, const int* __restrict__ mask,
    const unsigned short* __restrict__ Mg, const unsigned short* __restrict__ vwg,
    unsigned short* __restrict__ X) {
  __shared__ unsigned short Ml[64 * WPAD];        // 9216 B
  __shared__ unsigned short Vw[64 * WPAD];        // 9216 B
  __shared__ unsigned short scr[8][16 * WPAD];    // U then o (per wave) 18432 B

  const int tid = threadIdx.x;
  const int l = tid & 63, w = tid >> 6;
  const int lr = l & 15, lg = l >> 4;

  const int tok = blockIdx.x * 8 + w;
  const size_t tb = (size_t)tok * 1024;
  const int off = lr * 64 + lg * 8;

  // ---- issue data loads first (long pole) ----
  const float4 qa = *(const float4*)(q + tb + off);
  const float4 qb = *(const float4*)(q + tb + off + 4);
  const float4 qc = *(const float4*)(q + tb + off + 32);
  const float4 qd = *(const float4*)(q + tb + off + 36);
  const float4 ka = *(const float4*)(k + tb + off);
  const float4 kb = *(const float4*)(k + tb + off + 4);
  const float4 kc = *(const float4*)(k + tb + off + 32);
  const float4 kd = *(const float4*)(k + tb + off + 36);
  const float4 va = *(const float4*)(v + tb + off);
  const float4 vb = *(const float4*)(v + tb + off + 4);
  const float4 vc = *(const float4*)(v + tb + off + 32);
  const float4 vd = *(const float4*)(v + tb + off + 36);
  const int4 mk4 = *(const int4*)(mask + (size_t)tok * 256 + lr * 16 + lg * 4);

  // ---- stage weights into LDS (block-wide, once; 512 threads -> 1 uint4 each) ----
  {
    const int row = tid >> 3, c0 = (tid & 7) * 8;
    *(uint4*)&Ml[row * WPAD + c0] = *(const uint4*)(Mg + row * 64 + c0);
    *(uint4*)&Vw[row * WPAD + c0] = *(const uint4*)(vwg + row * 64 + c0);
  }
  __syncthreads();

  // ---- pack raw fragments ----
  const bf16x8 ak0 = pack8(ka, kb), ak1 = pack8(kc, kd);
  const bf16x8 av0 = pack8(va, vb), av1 = pack8(vc, vd);
  const bf16x8 aq0 = pack8(qa, qb), aq1 = pack8(qc, qd);

  // ---- U = Rk @ M^T ; v4 = Rv @ vw^T ----
  f32x4 accu[4], accv[4];
#pragma unroll
  for (int n = 0; n < 4; ++n) {
    const int wrow = (n * 16 + lr) * WPAD;
    f32x4 z = {};
    bf16x8 bm0 = *(const bf16x8*)&Ml[wrow + lg * 8];
    bf16x8 bm1 = *(const bf16x8*)&Ml[wrow + 32 + lg * 8];
    accu[n] = __builtin_amdgcn_mfma_f32_16x16x32_bf16(ak0, bm0, z, 0, 0, 0);
    accu[n] = __builtin_amdgcn_mfma_f32_16x16x32_bf16(ak1, bm1, accu[n], 0, 0, 0);
    bf16x8 bw0 = *(const bf16x8*)&Vw[wrow + lg * 8];
    bf16x8 bw1 = *(const bf16x8*)&Vw[wrow + 32 + lg * 8];
    accv[n] = __builtin_amdgcn_mfma_f32_16x16x32_bf16(av0, bw0, z, 0, 0, 0);
    accv[n] = __builtin_amdgcn_mfma_f32_16x16x32_bf16(av1, bw1, accv[n], 0, 0, 0);
  }

  // ---- spill U (row-major [g][e]) to wave-private LDS ----
  unsigned short* U = scr[w];
#pragma unroll
  for (int n = 0; n < 4; ++n)
#pragma unroll
    for (int r = 0; r < 4; ++r)
      U[(lg * 4 + r) * WPAD + n * 16 + lr] = f2bf(accu[n][r]);

  // ---- S^T = U @ Rq^T  (C: row=g=lg*4+r, col=h=lr) ----
  const bf16x8 ua0 = *(const bf16x8*)&U[lr * WPAD + lg * 8];
  const bf16x8 ua1 = *(const bf16x8*)&U[lr * WPAD + 32 + lg * 8];
  f32x4 z4 = {};
  f32x4 st = __builtin_amdgcn_mfma_f32_16x16x32_bf16(ua0, aq0, z4, 0, 0, 0);
  st = __builtin_amdgcn_mfma_f32_16x16x32_bf16(ua1, aq1, st, 0, 0, 0);

  // ---- softmax over g ----
  const int mk[4] = {mk4.x, mk4.y, mk4.z, mk4.w};
  float sv[4];
#pragma unroll
  for (int r = 0; r < 4; ++r)
    sv[r] = (mk[r] != 0) ? st[r] * 0.125f : -1e30f;
  float mx = fmaxf(fmaxf(sv[0], sv[1]), fmaxf(sv[2], sv[3]));
  mx = fmaxf(mx, __shfl_xor(mx, 16));
  mx = fmaxf(mx, __shfl_xor(mx, 32));
  float e[4];
  float sm = 0.f;
#pragma unroll
  for (int r = 0; r < 4; ++r) { e[r] = __expf(sv[r] - mx); sm += e[r]; }
  sm += __shfl_xor(sm, 16);
  sm += __shfl_xor(sm, 32);
  const float inv = 1.0f / sm;
#pragma unroll
  for (int r = 0; r < 4; ++r) e[r] *= inv;

  // ---- PV A-fragment: lane needs P[h=lr][g=lg*8+j] (lanes lg>=2 zero) ----
  bf16x8 apv;
#pragma unroll
  for (int j = 0; j < 8; ++j) {
    const int srcg = (lg * 2 + (j >> 2)) & 3;
    const float pv = __shfl(e[j & 3], lr + srcg * 16, 64);
    apv[j] = (short)((lg < 2) ? f2bf(pv) : (unsigned short)0);
  }

  // ---- PV B-fragments from accv via shuffles (v4[g][d], g=(lg&1)*8+j, d=n*16+lr) ----
  // source lane: lr + ((lg&1)*2 + (j>>2))*16, source reg: accv[n][j&3]
  const int s0 = lr + ((lg & 1) * 2) * 16;
  const int s1 = s0 + 16;
  f32x4 o[4];
#pragma unroll
  for (int n = 0; n < 4; ++n) {
    bf16x8 bv;
#pragma unroll
    for (int j = 0; j < 8; ++j) {
      const float xv = __shfl(accv[n][j & 3], (j < 4) ? s0 : s1, 64);
      bv[j] = (short)f2bf(xv);
    }
    f32x4 z = {};
    o[n] = __builtin_amdgcn_mfma_f32_16x16x32_bf16(apv, bv, z, 0, 0, 0);
  }

  // ---- transpose O through LDS (reuse U region), then vector stores ----
#pragma unroll
  for (int n = 0; n < 4; ++n)
#pragma unroll
    for (int r = 0; r < 4; ++r)
      U[(lg * 4 + r) * WPAD + n * 16 + lr] = f2bf(o[n][r]);

  const int nb = tok >> 12, lpos = tok & (LSEQ - 1);
#pragma unroll
  for (int it = 0; it < 2; ++it) {
    const int idx = it * 64 + l;
    const int h = idx >> 3, c = idx & 7;
    const uint4 val = *(const uint4*)&U[h * WPAD + c * 8];
    *(uint4*)&X[((size_t)(nb * 16 + h) * LSEQ + lpos) * 64 + c * 8] = val;
  }
}

// ---------------- final FC: OUT[16384x1024] = X @ fc_w^T + b (bf16 MFMA) ----------------
__global__ __launch_bounds__(256) void gemm_fc(const unsigned short* __restrict__ A,
                                               const unsigned short* __restrict__ B,
                                               const float* __restrict__ bias,
                                               float* __restrict__ C) {
  __shared__ unsigned short sA[128 * 32];
  __shared__ unsigned short sB[128 * 32];
  const int tid = threadIdx.x;
  const int l = tid & 63, w = tid >> 6;
  const int wr = w >> 1, wc = w & 1;

  const int bid = blockIdx.x;
  const int wg = (bid & 7) * 128 + (bid >> 3);
  const int tm = (wg >> 3) * 128;
  const int tn = (wg & 7) * 128;

  f32x4 acc[4][4] = {};

  const int r0 = w * 16 + (l >> 2);
  const int c8 = (l & 3) * 8;

  for (int kt = 0; kt < 32; ++kt) {
    const int k0 = kt * 32;
#pragma unroll
    for (int s = 0; s < 2; ++s) {
      async16(A + (size_t)(tm + s * 64 + r0) * 1024 + k0 + c8,
              (char*)sA + s * 4096 + w * 1024);
      async16(B + (size_t)(tn + s * 64 + r0) * 1024 + k0 + c8,
              (char*)sB + s * 4096 + w * 1024);
    }
    __syncthreads();

    bf16x8 af[4], bfr[4];
#pragma unroll
    for (int fi = 0; fi < 4; ++fi)
      af[fi] = *(const bf16x8*)((const char*)sA +
                                (wr * 64 + fi * 16 + (l & 15)) * 64 + (l >> 4) * 16);
#pragma unroll
    for (int fj = 0; fj < 4; ++fj)
      bfr[fj] = *(const bf16x8*)((const char*)sB +
                                 (wc * 64 + fj * 16 + (l & 15)) * 64 + (l >> 4) * 16);
#pragma unroll
    for (int fi = 0; fi < 4; ++fi)
#pragma unroll
      for (int fj = 0; fj < 4; ++fj)
        acc[fi][fj] = __builtin_amdgcn_mfma_f32_16x16x32_bf16(af[fi], bfr[fj],
                                                              acc[fi][fj], 0, 0, 0);
    __syncthreads();
  }

#pragma unroll
  for (int fj = 0; fj < 4; ++fj) {
    const int col = tn + wc * 64 + fj * 16 + (l & 15);
    const float bv = bias[col];
#pragma unroll
    for (int fi = 0; fi < 4; ++fi) {
#pragma unroll
      for (int r = 0; r < 4; ++r) {
        const int row = tm + wr * 64 + fi * 16 + (l >> 4) * 4 + r;
        C[(size_t)row * 1024 + col] = acc[fi][fj][r] + bv;
      }
    }
  }
}

extern "C" void kernel_launch(void* const* d_in, const int* in_sizes, int n_in,
                              void* d_out, int out_size, void* d_ws, size_t ws_size,
                              hipStream_t stream) {
  (void)in_sizes; (void)n_in; (void)out_size; (void)ws_size;
  const float* q   = (const float*)d_in[0];
  const float* k   = (const float*)d_in[1];
  const float* v   = (const float*)d_in[2];
  const int*  mask = (const int*)d_in[3];
  const float* qw  = (const float*)d_in[4];
  const float* kw  = (const float*)d_in[5];
  const float* vw  = (const float*)d_in[6];
  const float* fcw = (const float*)d_in[7];
  const float* fcb = (const float*)d_in[8];
  float* out = (float*)d_out;

  unsigned short* X   = (unsigned short*)d_ws;            // 16M bf16 = 32 MiB
  unsigned short* Wb  = X + (size_t)16 * 1024 * 1024;     // 1M bf16  =  2 MiB
  unsigned short* Mw  = Wb + (size_t)1024 * 1024;         // 4096 bf16 = 8 KiB
  unsigned short* vwb = Mw + 4096;                        // 4096 bf16 = 8 KiB

  cvt_bf16<<<dim3(1024), dim3(256), 0, stream>>>(fcw, Wb, 262144);
  prep_weights<<<dim3(1), dim3(1024), 0, stream>>>(qw, kw, vw, Mw, vwb);
  attn4<<<dim3(2048), dim3(512), 0, stream>>>(q, k, v, mask, Mw, vwb, X);
  gemm_fc<<<dim3(1024), dim3(256), 0, stream>>>(X, Wb, fcb, out);
}

// Round 5
// 116.533 us; speedup vs baseline: 1.0743x; 1.0743x over previous
//
#include <hip/hip_runtime.h>
#include <hip/hip_bf16.h>
#include <stdint.h>

#define TOKENS 16384   // N=4 * L=4096
#define LSEQ 4096
#define WPAD 72        // padded row length (shorts) for M/vw/U tiles

typedef short bf16x8 __attribute__((ext_vector_type(8)));
typedef float f32x4 __attribute__((ext_vector_type(4)));

typedef __attribute__((address_space(1))) void as1_t;
typedef __attribute__((address_space(3))) void as3_t;

__device__ __forceinline__ unsigned short f2bf(float x) {
  __hip_bfloat16 t = __float2bfloat16(x);
  return *reinterpret_cast<unsigned short*>(&t);
}

__device__ __forceinline__ bf16x8 pack8(float4 a, float4 b) {
  bf16x8 t;
  t[0] = (short)f2bf(a.x); t[1] = (short)f2bf(a.y);
  t[2] = (short)f2bf(a.z); t[3] = (short)f2bf(a.w);
  t[4] = (short)f2bf(b.x); t[5] = (short)f2bf(b.y);
  t[6] = (short)f2bf(b.z); t[7] = (short)f2bf(b.w);
  return t;
}

__device__ __forceinline__ void async16(const void* g, void* lds) {
  __builtin_amdgcn_global_load_lds((as1_t*)const_cast<void*>(g),
                                   (as3_t*)lds, 16, 0, 0);
}

// ---------------- fc_w f32 -> bf16 ----------------
__global__ __launch_bounds__(256) void cvt_bf16(const float* __restrict__ s,
                                                unsigned short* __restrict__ d,
                                                int n4) {
  int i = blockIdx.x * 256 + threadIdx.x;
  if (i < n4) {
    float4 f = ((const float4*)s)[i];
    union { unsigned short us[4]; uint2 u2; } pk;
    pk.us[0] = f2bf(f.x); pk.us[1] = f2bf(f.y);
    pk.us[2] = f2bf(f.z); pk.us[3] = f2bf(f.w);
    ((uint2*)d)[i] = pk.u2;
  }
}

// ---------------- prep: M[f][e] = sum_d qw[d][f]*kw[d][e]; vw -> bf16 ----------------
__global__ __launch_bounds__(1024) void prep_weights(
    const float* __restrict__ qw, const float* __restrict__ kw,
    const float* __restrict__ vw, unsigned short* __restrict__ Mout,
    unsigned short* __restrict__ vwout) {
  __shared__ float ql[4096], kl[4096];
  const int t = threadIdx.x;
  ((float4*)ql)[t] = ((const float4*)qw)[t];
  ((float4*)kl)[t] = ((const float4*)kw)[t];
  {
    float4 f = ((const float4*)vw)[t];
    union { unsigned short us[4]; uint2 u2; } pk;
    pk.us[0] = f2bf(f.x); pk.us[1] = f2bf(f.y);
    pk.us[2] = f2bf(f.z); pk.us[3] = f2bf(f.w);
    ((uint2*)vwout)[t] = pk.u2;
  }
  __syncthreads();
  const int f = t >> 4;            // 0..63  (q raw dim)
  const int e0 = (t & 15) * 4;     // 0..60  (k raw dim block)
  float acc0 = 0.f, acc1 = 0.f, acc2 = 0.f, acc3 = 0.f;
#pragma unroll 8
  for (int d = 0; d < 64; ++d) {
    const float qv = ql[d * 64 + f];
    const float4 kv = *(const float4*)&kl[d * 64 + e0];
    acc0 += qv * kv.x; acc1 += qv * kv.y; acc2 += qv * kv.z; acc3 += qv * kv.w;
  }
  union { unsigned short us[4]; uint2 u2; } pk;
  pk.us[0] = f2bf(acc0); pk.us[1] = f2bf(acc1);
  pk.us[2] = f2bf(acc2); pk.us[3] = f2bf(acc3);
  *(uint2*)&Mout[f * 64 + e0] = pk.u2;
}

// ---------------- fused attention: TWO tokens per wave (interleaved ILP) ----------------
// S^T = (Rk @ M^T) @ Rq^T ; v4 = Rv @ vw^T ; O = P @ v4.
// mfma convention (HW-validated R2-R4): mfma(fragA(X), fragA(Y)) = X @ Y^T,
// fragA: lane holds X[row=l&15][k=(l>>4)*8+j]; C: col=l&15, row=(l>>4)*4+r.
__global__ __launch_bounds__(256, 4) void attn5(
    const float* __restrict__ q, const float* __restrict__ k,
    const float* __restrict__ v, const int* __restrict__ mask,
    const unsigned short* __restrict__ Mg, const unsigned short* __restrict__ vwg,
    unsigned short* __restrict__ X) {
  __shared__ unsigned short Ml[64 * WPAD];           // 9216 B
  __shared__ unsigned short Vw[64 * WPAD];           // 9216 B
  __shared__ unsigned short scr[4][2][16 * WPAD];    // per wave, per token: 18432 B

  const int tid = threadIdx.x;
  const int l = tid & 63, w = tid >> 6;
  const int lr = l & 15, lg = l >> 4;

  const int tok0 = blockIdx.x * 8 + w * 2;
  const int off = lr * 64 + lg * 8;

  // ---- issue ALL loads for both tokens up front ----
  float4 L[2][12];
  int4 mk4[2];
#pragma unroll
  for (int t = 0; t < 2; ++t) {
    const size_t tb = (size_t)(tok0 + t) * 1024;
    L[t][0] = *(const float4*)(q + tb + off);
    L[t][1] = *(const float4*)(q + tb + off + 4);
    L[t][2] = *(const float4*)(q + tb + off + 32);
    L[t][3] = *(const float4*)(q + tb + off + 36);
    L[t][4] = *(const float4*)(k + tb + off);
    L[t][5] = *(const float4*)(k + tb + off + 4);
    L[t][6] = *(const float4*)(k + tb + off + 32);
    L[t][7] = *(const float4*)(k + tb + off + 36);
    L[t][8] = *(const float4*)(v + tb + off);
    L[t][9] = *(const float4*)(v + tb + off + 4);
    L[t][10] = *(const float4*)(v + tb + off + 32);
    L[t][11] = *(const float4*)(v + tb + off + 36);
    mk4[t] = *(const int4*)(mask + (size_t)(tok0 + t) * 256 + lr * 16 + lg * 4);
  }

  // ---- stage weights into LDS (block-wide, once) ----
  {
    const int row = tid >> 2, c0 = (tid & 3) * 16;
    *(uint4*)&Ml[row * WPAD + c0]     = *(const uint4*)(Mg + row * 64 + c0);
    *(uint4*)&Ml[row * WPAD + c0 + 8] = *(const uint4*)(Mg + row * 64 + c0 + 8);
    *(uint4*)&Vw[row * WPAD + c0]     = *(const uint4*)(vwg + row * 64 + c0);
    *(uint4*)&Vw[row * WPAD + c0 + 8] = *(const uint4*)(vwg + row * 64 + c0 + 8);
  }
  __syncthreads();

  // ---- pack raw fragments (frees the float4s) ----
  bf16x8 aq0[2], aq1[2], ak0[2], ak1[2], av0[2], av1[2];
#pragma unroll
  for (int t = 0; t < 2; ++t) {
    aq0[t] = pack8(L[t][0], L[t][1]);  aq1[t] = pack8(L[t][2], L[t][3]);
    ak0[t] = pack8(L[t][4], L[t][5]);  ak1[t] = pack8(L[t][6], L[t][7]);
    av0[t] = pack8(L[t][8], L[t][9]);  av1[t] = pack8(L[t][10], L[t][11]);
  }

  // ---- U = Rk @ M^T ; v4 = Rv @ vw^T ; spill U per token ----
  f32x4 accv[2][4];
#pragma unroll
  for (int t = 0; t < 2; ++t) {
    f32x4 accu[4];
#pragma unroll
    for (int n = 0; n < 4; ++n) {
      const int wrow = (n * 16 + lr) * WPAD;
      f32x4 z = {};
      bf16x8 bm0 = *(const bf16x8*)&Ml[wrow + lg * 8];
      bf16x8 bm1 = *(const bf16x8*)&Ml[wrow + 32 + lg * 8];
      accu[n] = __builtin_amdgcn_mfma_f32_16x16x32_bf16(ak0[t], bm0, z, 0, 0, 0);
      accu[n] = __builtin_amdgcn_mfma_f32_16x16x32_bf16(ak1[t], bm1, accu[n], 0, 0, 0);
      bf16x8 bw0 = *(const bf16x8*)&Vw[wrow + lg * 8];
      bf16x8 bw1 = *(const bf16x8*)&Vw[wrow + 32 + lg * 8];
      accv[t][n] = __builtin_amdgcn_mfma_f32_16x16x32_bf16(av0[t], bw0, z, 0, 0, 0);
      accv[t][n] = __builtin_amdgcn_mfma_f32_16x16x32_bf16(av1[t], bw1, accv[t][n], 0, 0, 0);
    }
    unsigned short* U = scr[w][t];
#pragma unroll
    for (int n = 0; n < 4; ++n)
#pragma unroll
      for (int r = 0; r < 4; ++r)
        U[(lg * 4 + r) * WPAD + n * 16 + lr] = f2bf(accu[n][r]);
  }

  // ---- S^T, softmax, PV, store per token (independent chains interleave) ----
#pragma unroll
  for (int t = 0; t < 2; ++t) {
    unsigned short* U = scr[w][t];
    const bf16x8 ua0 = *(const bf16x8*)&U[lr * WPAD + lg * 8];
    const bf16x8 ua1 = *(const bf16x8*)&U[lr * WPAD + 32 + lg * 8];
    f32x4 z4 = {};
    f32x4 st = __builtin_amdgcn_mfma_f32_16x16x32_bf16(ua0, aq0[t], z4, 0, 0, 0);
    st = __builtin_amdgcn_mfma_f32_16x16x32_bf16(ua1, aq1[t], st, 0, 0, 0);

    const int mk[4] = {mk4[t].x, mk4[t].y, mk4[t].z, mk4[t].w};
    float sv[4];
#pragma unroll
    for (int r = 0; r < 4; ++r)
      sv[r] = (mk[r] != 0) ? st[r] * 0.125f : -1e30f;
    float mx = fmaxf(fmaxf(sv[0], sv[1]), fmaxf(sv[2], sv[3]));
    mx = fmaxf(mx, __shfl_xor(mx, 16));
    mx = fmaxf(mx, __shfl_xor(mx, 32));
    float e[4];
    float sm = 0.f;
#pragma unroll
    for (int r = 0; r < 4; ++r) { e[r] = __expf(sv[r] - mx); sm += e[r]; }
    sm += __shfl_xor(sm, 16);
    sm += __shfl_xor(sm, 32);
    const float inv = 1.0f / sm;
#pragma unroll
    for (int r = 0; r < 4; ++r) e[r] *= inv;

    // PV A-fragment: lane needs P[h=lr][g=lg*8+j] (lanes lg>=2 zero)
    bf16x8 apv;
#pragma unroll
    for (int j = 0; j < 8; ++j) {
      const int srcg = (lg * 2 + (j >> 2)) & 3;
      const float pv = __shfl(e[j & 3], lr + srcg * 16, 64);
      apv[j] = (short)((lg < 2) ? f2bf(pv) : (unsigned short)0);
    }

    // PV B-fragments from accv via shuffles (v4[g][d], g=(lg&1)*8+j, d=n*16+lr)
    const int s0 = lr + ((lg & 1) * 2) * 16;
    const int s1 = s0 + 16;
    f32x4 o[4];
#pragma unroll
    for (int n = 0; n < 4; ++n) {
      bf16x8 bv;
#pragma unroll
      for (int j = 0; j < 8; ++j) {
        const float xv = __shfl(accv[t][n][j & 3], (j < 4) ? s0 : s1, 64);
        bv[j] = (short)f2bf(xv);
      }
      f32x4 z = {};
      o[n] = __builtin_amdgcn_mfma_f32_16x16x32_bf16(apv, bv, z, 0, 0, 0);
    }

    // transpose O through LDS (reuse U region), then vector stores
#pragma unroll
    for (int n = 0; n < 4; ++n)
#pragma unroll
      for (int r = 0; r < 4; ++r)
        U[(lg * 4 + r) * WPAD + n * 16 + lr] = f2bf(o[n][r]);

    const int tok = tok0 + t;
    const int nb = tok >> 12, lpos = tok & (LSEQ - 1);
#pragma unroll
    for (int it = 0; it < 2; ++it) {
      const int idx = it * 64 + l;
      const int h = idx >> 3, c = idx & 7;
      const uint4 val = *(const uint4*)&U[h * WPAD + c * 8];
      *(uint4*)&X[((size_t)(nb * 16 + h) * LSEQ + lpos) * 64 + c * 8] = val;
    }
  }
}

// ---------------- final FC: OUT[16384x1024] = X @ fc_w^T + b (bf16 MFMA) ----------------
__global__ __launch_bounds__(256) void gemm_fc(const unsigned short* __restrict__ A,
                                               const unsigned short* __restrict__ B,
                                               const float* __restrict__ bias,
                                               float* __restrict__ C) {
  __shared__ unsigned short sA[128 * 32];
  __shared__ unsigned short sB[128 * 32];
  const int tid = threadIdx.x;
  const int l = tid & 63, w = tid >> 6;
  const int wr = w >> 1, wc = w & 1;

  const int bid = blockIdx.x;
  const int wg = (bid & 7) * 128 + (bid >> 3);
  const int tm = (wg >> 3) * 128;
  const int tn = (wg & 7) * 128;

  f32x4 acc[4][4] = {};

  const int r0 = w * 16 + (l >> 2);
  const int c8 = (l & 3) * 8;

  for (int kt = 0; kt < 32; ++kt) {
    const int k0 = kt * 32;
#pragma unroll
    for (int s = 0; s < 2; ++s) {
      async16(A + (size_t)(tm + s * 64 + r0) * 1024 + k0 + c8,
              (char*)sA + s * 4096 + w * 1024);
      async16(B + (size_t)(tn + s * 64 + r0) * 1024 + k0 + c8,
              (char*)sB + s * 4096 + w * 1024);
    }
    __syncthreads();

    bf16x8 af[4], bfr[4];
#pragma unroll
    for (int fi = 0; fi < 4; ++fi)
      af[fi] = *(const bf16x8*)((const char*)sA +
                                (wr * 64 + fi * 16 + (l & 15)) * 64 + (l >> 4) * 16);
#pragma unroll
    for (int fj = 0; fj < 4; ++fj)
      bfr[fj] = *(const bf16x8*)((const char*)sB +
                                 (wc * 64 + fj * 16 + (l & 15)) * 64 + (l >> 4) * 16);
#pragma unroll
    for (int fi = 0; fi < 4; ++fi)
#pragma unroll
      for (int fj = 0; fj < 4; ++fj)
        acc[fi][fj] = __builtin_amdgcn_mfma_f32_16x16x32_bf16(af[fi], bfr[fj],
                                                              acc[fi][fj], 0, 0, 0);
    __syncthreads();
  }

#pragma unroll
  for (int fj = 0; fj < 4; ++fj) {
    const int col = tn + wc * 64 + fj * 16 + (l & 15);
    const float bv = bias[col];
#pragma unroll
    for (int fi = 0; fi < 4; ++fi) {
#pragma unroll
      for (int r = 0; r < 4; ++r) {
        const int row = tm + wr * 64 + fi * 16 + (l >> 4) * 4 + r;
        C[(size_t)row * 1024 + col] = acc[fi][fj][r] + bv;
      }
    }
  }
}

extern "C" void kernel_launch(void* const* d_in, const int* in_sizes, int n_in,
                              void* d_out, int out_size, void* d_ws, size_t ws_size,
                              hipStream_t stream) {
  (void)in_sizes; (void)n_in; (void)out_size; (void)ws_size;
  const float* q   = (const float*)d_in[0];
  const float* k   = (const float*)d_in[1];
  const float* v   = (const float*)d_in[2];
  const int*  mask = (const int*)d_in[3];
  const float* qw  = (const float*)d_in[4];
  const float* kw  = (const float*)d_in[5];
  const float* vw  = (const float*)d_in[6];
  const float* fcw = (const float*)d_in[7];
  const float* fcb = (const float*)d_in[8];
  float* out = (float*)d_out;

  unsigned short* X   = (unsigned short*)d_ws;            // 16M bf16 = 32 MiB
  unsigned short* Wb  = X + (size_t)16 * 1024 * 1024;     // 1M bf16  =  2 MiB
  unsigned short* Mw  = Wb + (size_t)1024 * 1024;         // 4096 bf16 = 8 KiB
  unsigned short* vwb = Mw + 4096;                        // 4096 bf16 = 8 KiB

  cvt_bf16<<<dim3(1024), dim3(256), 0, stream>>>(fcw, Wb, 262144);
  prep_weights<<<dim3(1), dim3(1024), 0, stream>>>(qw, kw, vw, Mw, vwb);
  attn5<<<dim3(2048), dim3(256), 0, stream>>>(q, k, v, mask, Mw, vwb, X);
  gemm_fc<<<dim3(1024), dim3(256), 0, stream>>>(X, Wb, fcb, out);
}